// Round 12
// baseline (1682.186 us; speedup 1.0000x reference)
//
#include <hip/hip_runtime.h>
#include <hip/hip_bf16.h>

typedef unsigned long long ull;
typedef __attribute__((ext_vector_type(8))) short short8;
typedef __attribute__((ext_vector_type(8))) __bf16 bf16x8;
typedef __attribute__((ext_vector_type(4))) float floatx4;

#define GLL16(gp, lp) __builtin_amdgcn_global_load_lds( \
  (__attribute__((address_space(1))) void*)(gp), \
  (__attribute__((address_space(3))) void*)(lp), 16, 0, 0)

#define WVM(N) asm volatile("s_waitcnt vmcnt(" #N ")" ::: "memory")

__device__ __forceinline__ floatx4 mfma16(short8 a, short8 b, floatx4 c){
  return __builtin_amdgcn_mfma_f32_16x16x32_bf16(
      __builtin_bit_cast(bf16x8, a), __builtin_bit_cast(bf16x8, b), c, 0, 0, 0);
}

// pack two f32 -> two bf16 (RNE) in one u32 (lo = a, hi = b)
__device__ __forceinline__ unsigned pkbf(float a, float b){
  unsigned ua = __float_as_uint(a), ub = __float_as_uint(b);
  ua += 0x7fffu + ((ua >> 16) & 1u);
  ub += 0x7fffu + ((ub >> 16) & 1u);
  return (ua >> 16) | (ub & 0xffff0000u);
}

// ---------------- avg-pool 3x3 -> channel-last padded bf16 ----------------
__global__ __launch_bounds__(256) void pool_kernel(const float* __restrict__ x,
                                                   unsigned short* __restrict__ out){
  __shared__ float xs[16*784];
  const int tid = threadIdx.x;
  const int b = blockIdx.x >> 5, cg = blockIdx.x & 31;
  const float* src = x + ((size_t)b*512 + cg*16)*784;
  for (int i=tid;i<16*784;i+=256) xs[i]=src[i];
  __syncthreads();
  unsigned* dst = (unsigned*)out + ((size_t)b*960)*256 + cg*8;
  for (int o=tid;o<30*32*8;o+=256){
    int cip = o & 7, pos = o >> 3;
    int row = pos >> 5, col = pos & 31;
    float s0=0.f, s1=0.f;
    if (row>=1 && row<=28 && col>=1 && col<=28){
      int h=row-1, w=col-1;
      const float* p0 = &xs[(cip*2)*784];
      const float* p1 = p0 + 784;
      #pragma unroll
      for (int dh=-1;dh<=1;++dh){ int hh=h+dh; if ((unsigned)hh<28u){
        #pragma unroll
        for (int dw=-1;dw<=1;++dw){ int ww=w+dw; if((unsigned)ww<28u){
          s0 += p0[hh*28+ww]; s1 += p1[hh*28+ww]; } } } }
      s0 /= 9.f; s1 /= 9.f;
    }
    dst[(size_t)pos*256 + cip] = pkbf(s0, s1);
  }
}

// ---------------- weight transform: OIHW f32 -> [tap][1024][CIN] bf16 ----------------
template<int CIN>
__global__ __launch_bounds__(256) void prep3x3(const float* __restrict__ w,
                                               unsigned short* __restrict__ Wt){
  __shared__ float wsm[CIN*9];
  const int co = blockIdx.x, tid = threadIdx.x;
  const float* src = w + (size_t)co*(CIN*9);
  for (int i=tid;i<CIN*9;i+=256) wsm[i]=src[i];
  __syncthreads();
  for (int o=tid;o<9*(CIN/2);o+=256){
    int t = o/(CIN/2), cp = o - t*(CIN/2);
    unsigned v = pkbf(wsm[(cp*2)*9+t], wsm[(cp*2+1)*9+t]);
    ((unsigned*)Wt)[(((size_t)t*1024+co)*CIN>>1) + cp] = v;
  }
}

// w3 [200][1024] f32 -> [256][1024] bf16, rows 200..255 zero
__global__ __launch_bounds__(256) void prep1x1(const float* __restrict__ w3,
                                               unsigned short* __restrict__ Wp){
  const int row = blockIdx.x, tid = threadIdx.x;
  unsigned* dst = (unsigned*)Wp + (size_t)row*512;
  if (row < 200){
    const float* src = w3 + (size_t)row*1024;
    for (int j=tid;j<512;j+=256) dst[j] = pkbf(src[2*j], src[2*j+1]);
  } else {
    for (int j=tid;j<512;j+=256) dst[j] = 0u;
  }
}

// ======== 3x3 conv v12: register fragment double-buffer (read t+1 under MFMA t) ========
// Grid 1024 = 8 co-groups(128co, XCD-pinned) x 32 b x 4 row-tiles; 2 blocks/CU.
// Block 256 thr = 4 waves (2 cog x 2 pg); wave tile 64co x 112px, acc[4][7] (AGPR).
// LDS 64KB: A 3 x 8KB tap-ring (staged 2 phases ahead), B 2 x 20KB dbuf (staged at t==1).
// Phase tt (18-phase chunk-pair unroll, all reg indices compile-time):
//   stage A(tt+2) [+B at t==1] -> WVM(own-count: older drained) ->
//   ds_read frags for phase tt+1 into set (tt+1)&1 (slot/buf data already resident) ->
//   28 MFMA on set tt&1 (independent of the reads -> both pipes overlap) -> barrier.
// Race matrix: slot s read in phase p (p+1=s mod 3) completes before MFMA(p+1) < barrier(p+1);
// overwritten by stage in p+3. B buf last read 3 phases before its re-stage. All 1-barrier safe.
template<int CIN>
__global__ __launch_bounds__(256, 2) void conv3x3_v12(
    const unsigned short* __restrict__ X,
    const unsigned short* __restrict__ Wt,
    const float* __restrict__ bias,
    unsigned short* __restrict__ Out)
{
  constexpr int NCH = CIN/32;                   // 16 or 32 (even)
  constexpr size_t CB = (size_t)CIN*2;
  constexpr size_t TAPSTR = (size_t)1024*CB;
  __shared__ char Als[24576];   // 3 x 8192 tap ring
  __shared__ char Bls[40960];   // 2 x 20480 dbuf

  const int tid = threadIdx.x;
  const int l = tid & 63, wv = tid >> 6;        // 4 waves
  const int cog = wv & 1, pg = wv >> 1;
  const int bid = blockIdx.x;
  const int co0 = (bid & 7) << 7;               // 128-co panel per XCD
  const int y = bid >> 3;                       // 0..127
  const int b = y >> 2, rb = y & 3;
  const int r0 = rb << 3;
  const bool active = (pg == 0) || (rb < 3);

  // staging lane pre-swizzle (linear LDS dest + inverse-swizzled source)
  const int sbyt = (l*16) ^ (((l>>3)&7)<<4);
  const int srow = sbyt >> 6;                   // 0..15 (64B rows within 1KB unit)
  const int sw   = sbyt & 63;

  // A: 8 units of 16 co rows; wave stages units wv*2, wv*2+1 (2 GLL/phase)
  const ull aS0 = (ull)Wt + (size_t)(co0 + (wv*2)*16   + srow)*CB + sw;
  const ull aS1 = (ull)Wt + (size_t)(co0 + (wv*2+1)*16 + srow)*CB + sw;
  // B: 20 units of 16 px (10 padded rows r0..r0+9 x 32 cols); wave stages units wv+4k
  ull bS[5];
  #pragma unroll
  for (int k=0;k<5;++k){
    int q = (wv + 4*k)*16 + srow;               // px 0..319
    int trow = q >> 5, tcol = q & 31;
    int ir = r0 + trow; if (ir > 29) ir = 29;
    bS[k] = (ull)X + ((size_t)b*960 + ir*32 + tcol)*CB + sw;
  }

  const int jl = l & 15, g = l >> 4;
  int paE[4];
  #pragma unroll
  for (int m=0;m<4;++m){
    int xo = (cog*64 + m*16 + jl)*64 + g*16;
    paE[m] = xo ^ (((xo>>7)&7)<<4);
  }
  int pbS[3][7];
  #pragma unroll
  for (int f=0;f<7;++f){
    int p = pg*112 + f*16 + jl;
    int hl = p/28, cl = p - hl*28;
    #pragma unroll
    for (int ss=0;ss<3;++ss){
      int xo = (hl*32 + cl + ss)*64 + g*16;
      pbS[ss][f] = xo ^ (((xo>>7)&7)<<4);       // + rr*2048 + buf*20480 post-swz (safe bits)
    }
  }

  floatx4 acc[4][7];
  #pragma unroll
  for (int m=0;m<4;++m)
    #pragma unroll
    for (int f=0;f<7;++f) acc[m][f] = (floatx4){0.f,0.f,0.f,0.f};

  short8 fa[2][4], fb[2][7];                    // fragment double-buffer (compile-time idx)

  // ---- prologue: B(c0)->buf0; A tap0->slot0, tap1->slot1; read phase-0 frags -> set 0 ----
  #pragma unroll
  for (int k=0;k<5;++k) GLL16((const void*)bS[k], Bls + (wv + 4*k)*1024);
  GLL16((const void*)aS0,            Als +        (wv*2)*1024);
  GLL16((const void*)aS1,            Als +        (wv*2+1)*1024);
  GLL16((const void*)(aS0 + TAPSTR), Als + 8192 + (wv*2)*1024);
  GLL16((const void*)(aS1 + TAPSTR), Als + 8192 + (wv*2+1)*1024);
  WVM(2);                                       // B0 + tap0 landed; tap1 floats
  __builtin_amdgcn_s_barrier();
  if (active){
    #pragma unroll
    for (int m=0;m<4;++m) fa[0][m] = *(const short8*)(Als + paE[m]);
    #pragma unroll
    for (int f=0;f<7;++f) fb[0][f] = *(const short8*)(Bls + pbS[0][f]);
  }

  #pragma unroll 1
  for (int c=0;c<NCH;c+=2){
    #pragma unroll
    for (int tt=0;tt<18;++tt){
      const int t  = tt % 9;
      const int ch = c + tt/9;
      // --- stage A for phase tt+2 (tap (t+2)%9, chunk ch+(t>=7)) into slot (tt+2)%3 ---
      {
        const int stTap = (t<7) ? t+2 : t-7;
        const size_t aoff = (size_t)stTap*TAPSTR + (size_t)(ch + (t>=7))*64;
        const int sd = ((tt+2)%3)*8192;
        GLL16((const void*)(aS0 + aoff), Als + sd + (wv*2)*1024);
        GLL16((const void*)(aS1 + aoff), Als + sd + (wv*2+1)*1024);
      }
      // --- stage B(ch+1) at t==1 into buf (ch+1)&1 (last pair stages guard garbage) ---
      if (t == 1){
        #pragma unroll
        for (int k=0;k<5;++k)
          GLL16((const void*)(bS[k] + (size_t)(ch+1)*64),
                Bls + (((ch+1)&1)*20480) + (wv + 4*k)*1024);
      }
      // --- counted wait: all stages older than this phase's drained (slot (tt+1)%3 ready) ---
      if (t == 1) { WVM(7); } else { WVM(2); }
      // --- ds_read frags for phase tt+1 into set (tt+1)&1 (independent of MFMAs below) ---
      if (active){
        const int tn  = (t+1) % 9;
        const int rrn = tn/3, ssn = tn - rrn*3;
        const char* ap = Als + ((tt+1)%3)*8192;
        const int bb = (((tt+1)/9)&1)*20480;
        #pragma unroll
        for (int m=0;m<4;++m) fa[(tt+1)&1][m] = *(const short8*)(ap + paE[m]);
        #pragma unroll
        for (int f=0;f<7;++f)
          fb[(tt+1)&1][f] = *(const short8*)(Bls + bb + pbS[ssn][f] + rrn*2048);
      }
      // --- 28 MFMA on set tt&1 (read last phase; compiler orders via lgkm counts) ---
      if (active){
        __builtin_amdgcn_s_setprio(1);
        #pragma unroll
        for (int f=0;f<7;++f){
          acc[0][f] = mfma16(fa[tt&1][0], fb[tt&1][f], acc[0][f]);
          acc[1][f] = mfma16(fa[tt&1][1], fb[tt&1][f], acc[1][f]);
          acc[2][f] = mfma16(fa[tt&1][2], fb[tt&1][f], acc[2][f]);
          acc[3][f] = mfma16(fa[tt&1][3], fb[tt&1][f], acc[3][f]);
        }
        __builtin_amdgcn_s_setprio(0);
      }
      __builtin_amdgcn_s_barrier();
    }
  }

  if (!active) return;

  // ---- epilogue: bias + ReLU + bf16 pack ----
  #pragma unroll
  for (int m=0;m<4;++m){
    const int coL = cog*64 + m*16 + g*4;
    const float4 bv4 = *(const float4*)&bias[co0 + coL];
    #pragma unroll
    for (int f=0;f<7;++f){
      int pp = pg*112 + f*16 + jl;
      int hl = pp/28, cl = pp - hl*28;
      float v0 = fmaxf(acc[m][f][0] + bv4.x, 0.f);
      float v1 = fmaxf(acc[m][f][1] + bv4.y, 0.f);
      float v2 = fmaxf(acc[m][f][2] + bv4.z, 0.f);
      float v3 = fmaxf(acc[m][f][3] + bv4.w, 0.f);
      uint2 pk; pk.x = pkbf(v0,v1); pk.y = pkbf(v2,v3);
      size_t oa = ((size_t)b*960 + (size_t)(r0 + hl + 1)*32 + (cl + 1))*1024 + (co0 + coL);
      *(uint2*)(Out + oa) = pk;
    }
  }
}

// ---------------- 1x1 conv via MFMA ----------------
template<int CIN, bool K3, bool BF16OUT>
__global__ __launch_bounds__(512, 2) void conv_mfma(
    const unsigned short* __restrict__ X,
    const unsigned short* __restrict__ Wt,
    const float* __restrict__ bias, int biasN,
    void* __restrict__ Out)
{
  constexpr int T9 = K3 ? 9 : 1;
  constexpr int NA = K3 ? 9 : 1;
  __shared__ short Als[T9*4096];
  __shared__ short Bls[10240];
  __shared__ float biasLs[128];

  const int tid = threadIdx.x;
  const int l = tid & 63, wv = tid >> 6;
  const int wc = wv & 3, wp = wv >> 2;
  const int co0 = blockIdx.x << 7;
  const int by = blockIdx.y;
  const int b = by >> 2, rb = by & 3;
  const int r0 = rb << 3;
  const int nrh = (rb < 3) ? 10 : 6;
  const int NB = 2*nrh;
  const bool active = (wp == 0) || (rb < 3);

  if (tid < 128) biasLs[tid] = (co0 + tid < biasN) ? bias[co0 + tid] : 0.f;

  const size_t laneOff = (size_t)(l >> 2)*(CIN*2) + (size_t)(l & 3)*16;

  ull aB[NA];
  #pragma unroll
  for (int j=0;j<NA;++j){
    int k = wv*NA + j;
    int t = K3 ? (k >> 3) : 0;
    int cog2 = K3 ? (k & 7) : k;
    aB[j] = (ull)Wt + ((size_t)(t*1024 + co0 + cog2*16)*(CIN*2)) + laneOff;
  }
  const ull xBase = (ull)X + ((size_t)b*960)*(CIN*2) + (size_t)(r0*32)*(CIN*2) + laneOff;
  ull bB0=0, bB1=0, bB2=0; int nb=0;
  if (wv < NB)      { bB0 = xBase + (size_t)(wv*16)*(CIN*2);      nb = 1; }
  if (wv + 8 < NB)  { bB1 = xBase + (size_t)((wv+8)*16)*(CIN*2);  nb = 2; }
  if (wv + 16 < NB) { bB2 = xBase + (size_t)((wv+16)*16)*(CIN*2); nb = 3; }

  const int jl = l & 15, g = l >> 4;
  int paE[2];
  #pragma unroll
  for (int m=0;m<2;++m) paE[m] = (wc*32 + m*16 + jl)*32 + g*8;
  int pbE[7], ph[7], pc[7];
  #pragma unroll
  for (int f=0;f<7;++f){
    int p = wp*112 + f*16 + jl;
    int hl = p / 28, cl = p - hl*28;
    ph[f]=hl; pc[f]=cl;
    pbE[f] = (hl*32 + cl)*32 + g*8;
  }

  floatx4 acc[2][7];
  #pragma unroll
  for (int m=0;m<2;++m)
    #pragma unroll
    for (int f=0;f<7;++f) acc[m][f] = (floatx4){0.f,0.f,0.f,0.f};

  const int NCH = CIN/32;
  for (int c=0;c<NCH;++c){
    if (c) __syncthreads();
    const size_t cOff = (size_t)c*64;
    #pragma unroll
    for (int j=0;j<NA;++j)
      GLL16((const void*)(aB[j] + cOff), (char*)Als + (wv*NA + j)*1024);
    GLL16((const void*)(bB0 + cOff), (char*)Bls + wv*1024);
    if (nb > 1) GLL16((const void*)(bB1 + cOff), (char*)Bls + (wv+8)*1024);
    if (nb > 2) GLL16((const void*)(bB2 + cOff), (char*)Bls + (wv+16)*1024);
    __syncthreads();
    if (active){
      #pragma unroll
      for (int t=0;t<T9;++t){
        const int tA = t*4096;
        const int tB = K3 ? (((t/3)*32 + (t - (t/3)*3))*32) : ((1*32+1)*32);
        short8 a0 = *(const short8*)&Als[tA + paE[0]];
        short8 a1 = *(const short8*)&Als[tA + paE[1]];
        #pragma unroll
        for (int f=0;f<7;++f){
          short8 bvv = *(const short8*)&Bls[tB + pbE[f]];
          acc[0][f] = mfma16(a0, bvv, acc[0][f]);
          acc[1][f] = mfma16(a1, bvv, acc[1][f]);
        }
      }
    }
  }

  if (!active) return;

  #pragma unroll
  for (int m=0;m<2;++m){
    const int coL = wc*32 + m*16 + g*4;
    const float4 bv4 = *(const float4*)&biasLs[coL];
    #pragma unroll
    for (int f=0;f<7;++f){
      float v0 = acc[m][f][0] + bv4.x;
      float v1 = acc[m][f][1] + bv4.y;
      float v2 = acc[m][f][2] + bv4.z;
      float v3 = acc[m][f][3] + bv4.w;
      if constexpr (BF16OUT){
        v0=fmaxf(v0,0.f); v1=fmaxf(v1,0.f); v2=fmaxf(v2,0.f); v3=fmaxf(v3,0.f);
        uint2 pk; pk.x = pkbf(v0,v1); pk.y = pkbf(v2,v3);
        size_t oa = ((size_t)b*960 + (size_t)(r0 + ph[f] + 1)*32 + (pc[f]+1))*1024 + (co0 + coL);
        *(uint2*)((unsigned short*)Out + oa) = pk;
      } else {
        int co = co0 + coL;
        if (co < 200){
          int p = wp*112 + f*16 + jl;
          size_t oa = ((size_t)b*784 + (size_t)(r0*28) + p)*200 + co;
          float4 ov; ov.x=v0; ov.y=v1; ov.z=v2; ov.w=v3;
          *(float4*)((float*)Out + oa) = ov;
        }
      }
    }
  }
}

// ---------------- logits ----------------
__global__ __launch_bounds__(256) void logits_kernel(const float* __restrict__ outC,
                                                     float* __restrict__ dst){
  const int b = blockIdx.x, seg = blockIdx.y;
  const int co = threadIdx.x;
  if (co >= 200) return;
  const float* base = outC + ((size_t)b*784 + seg*98)*200 + co;
  float s = 0.f;
  for (int p=0;p<98;++p) s += base[(size_t)p*200];
  atomicAdd(&dst[b*200+co], s*(1.f/784.f));
}

// ---------------- attention -> mask ----------------
__global__ __launch_bounds__(256) void atten_kernel(const float* __restrict__ outC,
                                                    const int* __restrict__ label,
                                                    float* __restrict__ mask){
  __shared__ float al[784];
  __shared__ float redn[256], redx[256];
  __shared__ unsigned char lab[200];
  const int b = blockIdx.x, tid = threadIdx.x;
  for (int i=tid;i<200;i+=256) lab[i] = label[b*200+i] > 0 ? 1 : 0;
  __syncthreads();
  for (int p=tid;p<784;p+=256){
    const float* row = outC + ((size_t)b*784+p)*200;
    float m = -__builtin_inff();
    for (int c=0;c<200;++c) if (lab[c]) m = fmaxf(m, row[c]);
    al[p] = fmaxf(m, 0.f);
  }
  __syncthreads();
  float mn = __builtin_inff(), mx = -__builtin_inff();
  for (int p=tid;p<784;p+=256){ float v=al[p]; mn=fminf(mn,v); mx=fmaxf(mx,v); }
  redn[tid]=mn; redx[tid]=mx; __syncthreads();
  for (int s2=128;s2>0;s2>>=1){
    if (tid<s2){ redn[tid]=fminf(redn[tid],redn[tid+s2]); redx[tid]=fmaxf(redx[tid],redx[tid+s2]); }
    __syncthreads();
  }
  mn = redn[0]; mx = redx[0];
  for (int p=tid;p<784;p+=256){
    float nrm = (al[p]-mn)/(mx-mn);
    mask[b*784+p] = (nrm >= 0.6f) ? 0.f : 1.f;
  }
}

// ---------------- erase ----------------
__global__ __launch_bounds__(256) void erase_kernel(const unsigned short* __restrict__ feats,
                                                    const float* __restrict__ mask,
                                                    unsigned short* __restrict__ dst){
  const int blk = blockIdx.x; const int b = blk/30, row = blk - b*30;
  const size_t base = ((size_t)b*960 + row*32)*512;
  for (int i=threadIdx.x; i<4096; i+=256){
    int col = i >> 7;
    float mv = 0.f;
    if (row>=1 && row<=28 && col>=1 && col<=28) mv = mask[b*784 + (row-1)*28 + (col-1)];
    uint2 v = make_uint2(0u,0u);
    if (mv > 0.5f) v = *(const uint2*)(feats + base + (size_t)i*4);
    *(uint2*)(dst + base + (size_t)i*4) = v;
  }
}

extern "C" void kernel_launch(void* const* d_in, const int* in_sizes, int n_in,
                              void* d_out, int out_size, void* d_ws, size_t ws_size,
                              hipStream_t stream){
  (void)in_sizes; (void)n_in; (void)out_size; (void)ws_size;
  const float* x   = (const float*)d_in[0];
  const int* label = (const int*)d_in[1];
  const float* w1a = (const float*)d_in[2];  const float* b1a = (const float*)d_in[3];
  const float* w2a = (const float*)d_in[4];  const float* b2a = (const float*)d_in[5];
  const float* w3a = (const float*)d_in[6];  const float* b3a = (const float*)d_in[7];
  const float* w1b = (const float*)d_in[8];  const float* b1b = (const float*)d_in[9];
  const float* w2b = (const float*)d_in[10]; const float* b2b = (const float*)d_in[11];
  const float* w3b = (const float*)d_in[12]; const float* b3b = (const float*)d_in[13];

  char* ws = (char*)d_ws;
  unsigned short* WtS = (unsigned short*)(ws);                 // [9][1024][512]  bf16 (+4KB guard)
  unsigned short* WtL = (unsigned short*)(ws + 9441280);       // [9][1024][1024] bf16 (+4KB guard)
  unsigned short* W3p = (unsigned short*)(ws + 28319744);      // [256][1024]     bf16 (+4KB guard)
  unsigned short* F   = (unsigned short*)(ws + 28848128);      // feats [32][960][512] (+4KB guard)
  unsigned short* G1  = (unsigned short*)(ws + 60309504);      // [32][960][1024] (+4KB guard)
  unsigned short* G2  = (unsigned short*)(ws + 123228160);     // [32][960][1024] (+4KB guard)
  float* outC  = (float*)(ws + 186146816);                     // [32][784][200] f32
  float* maskB = (float*)(ws + 206217216);                     // [32][784] f32
  float* logA = (float*)d_out;
  float* logB = logA + 6400;

  hipMemsetAsync(G1, 0, 62914560, stream);
  hipMemsetAsync(G2, 0, 62914560, stream);
  hipMemsetAsync(d_out, 0, 51200, stream);

  pool_kernel<<<1024,256,0,stream>>>(x, F);

  // ---- path A ----
  prep3x3<512><<<1024,256,0,stream>>>(w1a, WtS);
  conv3x3_v12<512><<<1024,256,0,stream>>>(F, WtS, b1a, G1);
  prep3x3<1024><<<1024,256,0,stream>>>(w2a, WtL);
  conv3x3_v12<1024><<<1024,256,0,stream>>>(G1, WtL, b2a, G2);
  prep1x1<<<256,256,0,stream>>>(w3a, W3p);
  conv_mfma<1024,false,false><<<dim3(2,128),512,0,stream>>>(G2, W3p, b3a, 200, outC);
  logits_kernel<<<dim3(32,8),256,0,stream>>>(outC, logA);
  atten_kernel<<<32,256,0,stream>>>(outC, label, maskB);
  erase_kernel<<<960,256,0,stream>>>(F, maskB, G1);

  // ---- path B ----
  prep3x3<512><<<1024,256,0,stream>>>(w1b, WtS);
  conv3x3_v12<512><<<1024,256,0,stream>>>(G1, WtS, b1b, G2);
  prep3x3<1024><<<1024,256,0,stream>>>(w2b, WtL);
  conv3x3_v12<1024><<<1024,256,0,stream>>>(G2, WtL, b2b, G1);
  prep1x1<<<256,256,0,stream>>>(w3b, W3p);
  conv_mfma<1024,false,false><<<dim3(2,128),512,0,stream>>>(G1, W3p, b3b, 200, outC);
  logits_kernel<<<dim3(32,8),256,0,stream>>>(outC, logB);
}

// Round 13
// 1529.460 us; speedup vs baseline: 1.0999x; 1.0999x over previous
//
#include <hip/hip_runtime.h>
#include <hip/hip_bf16.h>

typedef unsigned long long ull;
typedef __attribute__((ext_vector_type(8))) short short8;
typedef __attribute__((ext_vector_type(8))) __bf16 bf16x8;
typedef __attribute__((ext_vector_type(4))) float floatx4;

#define GLL16(gp, lp) __builtin_amdgcn_global_load_lds( \
  (__attribute__((address_space(1))) void*)(gp), \
  (__attribute__((address_space(3))) void*)(lp), 16, 0, 0)

#define WVM(N) asm volatile("s_waitcnt vmcnt(" #N ")" ::: "memory")

__device__ __forceinline__ floatx4 mfma16(short8 a, short8 b, floatx4 c){
  return __builtin_amdgcn_mfma_f32_16x16x32_bf16(
      __builtin_bit_cast(bf16x8, a), __builtin_bit_cast(bf16x8, b), c, 0, 0, 0);
}

// pack two f32 -> two bf16 (RNE) in one u32 (lo = a, hi = b)
__device__ __forceinline__ unsigned pkbf(float a, float b){
  unsigned ua = __float_as_uint(a), ub = __float_as_uint(b);
  ua += 0x7fffu + ((ua >> 16) & 1u);
  ub += 0x7fffu + ((ub >> 16) & 1u);
  return (ua >> 16) | (ub & 0xffff0000u);
}

// ---------------- avg-pool 3x3 -> channel-last padded bf16 ----------------
__global__ __launch_bounds__(256) void pool_kernel(const float* __restrict__ x,
                                                   unsigned short* __restrict__ out){
  __shared__ float xs[16*784];
  const int tid = threadIdx.x;
  const int b = blockIdx.x >> 5, cg = blockIdx.x & 31;
  const float* src = x + ((size_t)b*512 + cg*16)*784;
  for (int i=tid;i<16*784;i+=256) xs[i]=src[i];
  __syncthreads();
  unsigned* dst = (unsigned*)out + ((size_t)b*960)*256 + cg*8;
  for (int o=tid;o<30*32*8;o+=256){
    int cip = o & 7, pos = o >> 3;
    int row = pos >> 5, col = pos & 31;
    float s0=0.f, s1=0.f;
    if (row>=1 && row<=28 && col>=1 && col<=28){
      int h=row-1, w=col-1;
      const float* p0 = &xs[(cip*2)*784];
      const float* p1 = p0 + 784;
      #pragma unroll
      for (int dh=-1;dh<=1;++dh){ int hh=h+dh; if ((unsigned)hh<28u){
        #pragma unroll
        for (int dw=-1;dw<=1;++dw){ int ww=w+dw; if((unsigned)ww<28u){
          s0 += p0[hh*28+ww]; s1 += p1[hh*28+ww]; } } } }
      s0 /= 9.f; s1 /= 9.f;
    }
    dst[(size_t)pos*256 + cip] = pkbf(s0, s1);
  }
}

// ---------------- weight transform: OIHW f32 -> [tap][1024][CIN] bf16 ----------------
template<int CIN>
__global__ __launch_bounds__(256) void prep3x3(const float* __restrict__ w,
                                               unsigned short* __restrict__ Wt){
  __shared__ float wsm[CIN*9];
  const int co = blockIdx.x, tid = threadIdx.x;
  const float* src = w + (size_t)co*(CIN*9);
  for (int i=tid;i<CIN*9;i+=256) wsm[i]=src[i];
  __syncthreads();
  for (int o=tid;o<9*(CIN/2);o+=256){
    int t = o/(CIN/2), cp = o - t*(CIN/2);
    unsigned v = pkbf(wsm[(cp*2)*9+t], wsm[(cp*2+1)*9+t]);
    ((unsigned*)Wt)[(((size_t)t*1024+co)*CIN>>1) + cp] = v;
  }
}

// w3 [200][1024] f32 -> [256][1024] bf16, rows 200..255 zero
__global__ __launch_bounds__(256) void prep1x1(const float* __restrict__ w3,
                                               unsigned short* __restrict__ Wp){
  const int row = blockIdx.x, tid = threadIdx.x;
  unsigned* dst = (unsigned*)Wp + (size_t)row*512;
  if (row < 200){
    const float* src = w3 + (size_t)row*1024;
    for (int j=tid;j<512;j+=256) dst[j] = pkbf(src[2*j], src[2*j+1]);
  } else {
    for (int j=tid;j<512;j+=256) dst[j] = 0u;
  }
}

// ======== 3x3 conv v13: barrier-free chunks via wave-private A; 1 barrier per 9 phases ========
// Grid 896 = 4 co-panels(256co) x 32 b x 7 y-tiles(4 rows, exact — no waste); 2 blocks/CU.
// Block 256 thr = 4 waves; wave w owns co [w*64, w*64+64) x 112px (4 rows x 28), acc[4][7].
// LDS 72KB: A wave-PRIVATE 3-slot ring (4KB/slot, 12KB/wave, 48KB) staged 2 phases ahead —
//   GLL->ds_read ordered by the wave's OWN vmcnt, no barrier. B shared 2 x 12KB (6 rows x
//   32col x 32ci), staged once per chunk at t==4 into the other buf.
// Phase: stage A(t+2) 4 GLL [+B 3 GLL at t==4] -> WVM(t=4,5 and !lastc ? 11 : 8) ->
//   reads (4 A + 7 B) -> MFMA x28 (setprio). Barrier ONLY at t==8 (chunk end): bounds drift
//   so buf (c+1)&1 re-stage is WAR-safe; own-vmcnt (drained by t==6) makes B writes visible.
// Waves free-run within a chunk -> read bursts overlap MFMA bursts across waves/blocks.
template<int CIN>
__global__ __launch_bounds__(256, 2) void conv3x3_v13(
    const unsigned short* __restrict__ X,
    const unsigned short* __restrict__ Wt,
    const float* __restrict__ bias,
    unsigned short* __restrict__ Out)
{
  constexpr int NCH = CIN/32;
  constexpr size_t CB = (size_t)CIN*2;
  constexpr size_t TAPSTR = (size_t)1024*CB;
  __shared__ char Als[49152];   // 4 waves x 3 slots x 4KB (private: wave w at w*12288)
  __shared__ char Bls[24576];   // 2 x 12KB [6 rows][32 cols][32 ci]

  const int tid = threadIdx.x;
  const int l = tid & 63, wv = tid >> 6;        // 4 waves, each owns 64 co
  const int bid = blockIdx.x;
  const int co0 = (bid & 3) << 8;               // 256-co panel
  const int y = bid >> 2;                       // 0..223
  const int b = y & 31, yt = y >> 5;            // 32 img x 7 y-tiles
  const int r0 = yt << 2;                       // output rows r0..r0+3 (padded rows r0..r0+5)

  // staging lane pre-swizzle (linear LDS dest + inverse-swizzled source)
  const int sbyt = (l*16) ^ (((l>>3)&7)<<4);
  const int srow = sbyt >> 6;                   // 0..15 (64B rows within 1KB unit)
  const int sw   = sbyt & 63;

  // A sources: wave-private 64 co rows, 4 units of 16 rows
  ull aS[4];
  #pragma unroll
  for (int k=0;k<4;++k)
    aS[k] = (ull)Wt + (size_t)(co0 + wv*64 + k*16 + srow)*CB + sw;
  // B sources: 12 units of 16 px (6 padded rows r0..r0+5 x 32 cols, r0+5 <= 29: no clamp)
  ull bS[3];
  #pragma unroll
  for (int k=0;k<3;++k){
    int q = (wv + 4*k)*16 + srow;               // px 0..191
    int hr = q >> 5, col = q & 31;
    bS[k] = (ull)X + ((size_t)b*960 + (r0 + hr)*32 + col)*CB + sw;
  }

  const int jl = l & 15, g = l >> 4;
  int paE[4];
  #pragma unroll
  for (int m=0;m<4;++m){
    int xo = (m*16 + jl)*64 + g*16;             // within the wave's 4KB slot
    paE[m] = xo ^ (((xo>>7)&7)<<4);
  }
  int pbS[3][7];
  #pragma unroll
  for (int f=0;f<7;++f){
    int p = f*16 + jl;                          // px 0..111
    int hl = p/28, cl = p - hl*28;
    #pragma unroll
    for (int ss=0;ss<3;++ss){
      int xo = (hl*32 + cl + ss)*64 + g*16;
      pbS[ss][f] = xo ^ (((xo>>7)&7)<<4);       // + rr*2048 + buf*12288 post-swz (bits>=11)
    }
  }

  floatx4 acc[4][7];
  #pragma unroll
  for (int m=0;m<4;++m)
    #pragma unroll
    for (int f=0;f<7;++f) acc[m][f] = (floatx4){0.f,0.f,0.f,0.f};

  char* const myA = Als + wv*12288;

  // ---- prologue: B(c0)->buf0 (3 GLL); A tap0->slot0, tap1->slot1 (4 GLL each) ----
  #pragma unroll
  for (int k=0;k<3;++k) GLL16((const void*)bS[k], Bls + (wv + 4*k)*1024);
  #pragma unroll
  for (int k=0;k<4;++k) GLL16((const void*)aS[k],            myA +        k*1024);
  #pragma unroll
  for (int k=0;k<4;++k) GLL16((const void*)(aS[k] + TAPSTR), myA + 4096 + k*1024);
  WVM(4);                                       // B0 + A(tap0) landed; A(tap1) floats
  __builtin_amdgcn_s_barrier();

  #pragma unroll 1
  for (int c=0;c<NCH;++c){
    const bool lastc = (c == NCH-1);
    const char* Bp = Bls + (c&1)*12288;
    #pragma unroll
    for (int t=0;t<9;++t){
      const int rr = t/3, ss = t - rr*3;
      // --- stage A for phase p+2 (tap (t+2)%9, chunk c+(t>=7)) into private slot (t+2)%3 ---
      {
        const int stTap = (t<7) ? t+2 : t-7;
        const size_t aoff = (size_t)stTap*TAPSTR + (size_t)(c + (t>=7))*64;
        char* sd = myA + ((t+2)%3)*4096;
        #pragma unroll
        for (int k=0;k<4;++k)
          GLL16((const void*)(aS[k] + aoff), sd + k*1024);
      }
      // --- stage B(c+1) at t==4 into the other buf ---
      if (t == 4 && !lastc){
        #pragma unroll
        for (int k=0;k<3;++k)
          GLL16((const void*)(bS[k] + (size_t)(c+1)*64),
                Bls + (((c+1)&1)*12288) + (wv + 4*k)*1024);
      }
      // --- own-wave counted wait: slot t%3 (staged 2 phases ago) + B(c) landed ---
      if ((t == 4 || t == 5) && !lastc) { WVM(11); } else { WVM(8); }
      // --- fragment reads + MFMA (no barrier; private A, resident B) ---
      {
        const char* ap = myA + (t%3)*4096;
        short8 a0 = *(const short8*)(ap + paE[0]);
        short8 a1 = *(const short8*)(ap + paE[1]);
        short8 a2 = *(const short8*)(ap + paE[2]);
        short8 a3 = *(const short8*)(ap + paE[3]);
        short8 bv[7];
        #pragma unroll
        for (int f=0;f<7;++f)
          bv[f] = *(const short8*)(Bp + (pbS[ss][f] + rr*2048));
        __builtin_amdgcn_s_setprio(1);
        #pragma unroll
        for (int f=0;f<7;++f){
          acc[0][f] = mfma16(a0, bv[f], acc[0][f]);
          acc[1][f] = mfma16(a1, bv[f], acc[1][f]);
          acc[2][f] = mfma16(a2, bv[f], acc[2][f]);
          acc[3][f] = mfma16(a3, bv[f], acc[3][f]);
        }
        __builtin_amdgcn_s_setprio(0);
      }
      // --- single barrier per chunk: bounds drift for B WAR; B writes already vmcnt-drained ---
      if (t == 8) __builtin_amdgcn_s_barrier();
    }
  }

  // ---- epilogue: bias + ReLU + bf16 pack (all waves fully active) ----
  #pragma unroll
  for (int m=0;m<4;++m){
    const int coL = wv*64 + m*16 + g*4;
    const float4 bv4 = *(const float4*)&bias[co0 + coL];
    #pragma unroll
    for (int f=0;f<7;++f){
      int pp = f*16 + jl;
      int hl = pp/28, cl = pp - hl*28;
      float v0 = fmaxf(acc[m][f][0] + bv4.x, 0.f);
      float v1 = fmaxf(acc[m][f][1] + bv4.y, 0.f);
      float v2 = fmaxf(acc[m][f][2] + bv4.z, 0.f);
      float v3 = fmaxf(acc[m][f][3] + bv4.w, 0.f);
      uint2 pk; pk.x = pkbf(v0,v1); pk.y = pkbf(v2,v3);
      size_t oa = ((size_t)b*960 + (size_t)(r0 + hl + 1)*32 + (cl + 1))*1024 + (co0 + coL);
      *(uint2*)(Out + oa) = pk;
    }
  }
}

// ---------------- 1x1 conv via MFMA ----------------
template<int CIN, bool K3, bool BF16OUT>
__global__ __launch_bounds__(512, 2) void conv_mfma(
    const unsigned short* __restrict__ X,
    const unsigned short* __restrict__ Wt,
    const float* __restrict__ bias, int biasN,
    void* __restrict__ Out)
{
  constexpr int T9 = K3 ? 9 : 1;
  constexpr int NA = K3 ? 9 : 1;
  __shared__ short Als[T9*4096];
  __shared__ short Bls[10240];
  __shared__ float biasLs[128];

  const int tid = threadIdx.x;
  const int l = tid & 63, wv = tid >> 6;
  const int wc = wv & 3, wp = wv >> 2;
  const int co0 = blockIdx.x << 7;
  const int by = blockIdx.y;
  const int b = by >> 2, rb = by & 3;
  const int r0 = rb << 3;
  const int nrh = (rb < 3) ? 10 : 6;
  const int NB = 2*nrh;
  const bool active = (wp == 0) || (rb < 3);

  if (tid < 128) biasLs[tid] = (co0 + tid < biasN) ? bias[co0 + tid] : 0.f;

  const size_t laneOff = (size_t)(l >> 2)*(CIN*2) + (size_t)(l & 3)*16;

  ull aB[NA];
  #pragma unroll
  for (int j=0;j<NA;++j){
    int k = wv*NA + j;
    int t = K3 ? (k >> 3) : 0;
    int cog2 = K3 ? (k & 7) : k;
    aB[j] = (ull)Wt + ((size_t)(t*1024 + co0 + cog2*16)*(CIN*2)) + laneOff;
  }
  const ull xBase = (ull)X + ((size_t)b*960)*(CIN*2) + (size_t)(r0*32)*(CIN*2) + laneOff;
  ull bB0=0, bB1=0, bB2=0; int nb=0;
  if (wv < NB)      { bB0 = xBase + (size_t)(wv*16)*(CIN*2);      nb = 1; }
  if (wv + 8 < NB)  { bB1 = xBase + (size_t)((wv+8)*16)*(CIN*2);  nb = 2; }
  if (wv + 16 < NB) { bB2 = xBase + (size_t)((wv+16)*16)*(CIN*2); nb = 3; }

  const int jl = l & 15, g = l >> 4;
  int paE[2];
  #pragma unroll
  for (int m=0;m<2;++m) paE[m] = (wc*32 + m*16 + jl)*32 + g*8;
  int pbE[7], ph[7], pc[7];
  #pragma unroll
  for (int f=0;f<7;++f){
    int p = wp*112 + f*16 + jl;
    int hl = p / 28, cl = p - hl*28;
    ph[f]=hl; pc[f]=cl;
    pbE[f] = (hl*32 + cl)*32 + g*8;
  }

  floatx4 acc[2][7];
  #pragma unroll
  for (int m=0;m<2;++m)
    #pragma unroll
    for (int f=0;f<7;++f) acc[m][f] = (floatx4){0.f,0.f,0.f,0.f};

  const int NCH = CIN/32;
  for (int c=0;c<NCH;++c){
    if (c) __syncthreads();
    const size_t cOff = (size_t)c*64;
    #pragma unroll
    for (int j=0;j<NA;++j)
      GLL16((const void*)(aB[j] + cOff), (char*)Als + (wv*NA + j)*1024);
    GLL16((const void*)(bB0 + cOff), (char*)Bls + wv*1024);
    if (nb > 1) GLL16((const void*)(bB1 + cOff), (char*)Bls + (wv+8)*1024);
    if (nb > 2) GLL16((const void*)(bB2 + cOff), (char*)Bls + (wv+16)*1024);
    __syncthreads();
    if (active){
      #pragma unroll
      for (int t=0;t<T9;++t){
        const int tA = t*4096;
        const int tB = K3 ? (((t/3)*32 + (t - (t/3)*3))*32) : ((1*32+1)*32);
        short8 a0 = *(const short8*)&Als[tA + paE[0]];
        short8 a1 = *(const short8*)&Als[tA + paE[1]];
        #pragma unroll
        for (int f=0;f<7;++f){
          short8 bvv = *(const short8*)&Bls[tB + pbE[f]];
          acc[0][f] = mfma16(a0, bvv, acc[0][f]);
          acc[1][f] = mfma16(a1, bvv, acc[1][f]);
        }
      }
    }
  }

  if (!active) return;

  #pragma unroll
  for (int m=0;m<2;++m){
    const int coL = wc*32 + m*16 + g*4;
    const float4 bv4 = *(const float4*)&biasLs[coL];
    #pragma unroll
    for (int f=0;f<7;++f){
      float v0 = acc[m][f][0] + bv4.x;
      float v1 = acc[m][f][1] + bv4.y;
      float v2 = acc[m][f][2] + bv4.z;
      float v3 = acc[m][f][3] + bv4.w;
      if constexpr (BF16OUT){
        v0=fmaxf(v0,0.f); v1=fmaxf(v1,0.f); v2=fmaxf(v2,0.f); v3=fmaxf(v3,0.f);
        uint2 pk; pk.x = pkbf(v0,v1); pk.y = pkbf(v2,v3);
        size_t oa = ((size_t)b*960 + (size_t)(r0 + ph[f] + 1)*32 + (pc[f]+1))*1024 + (co0 + coL);
        *(uint2*)((unsigned short*)Out + oa) = pk;
      } else {
        int co = co0 + coL;
        if (co < 200){
          int p = wp*112 + f*16 + jl;
          size_t oa = ((size_t)b*784 + (size_t)(r0*28) + p)*200 + co;
          float4 ov; ov.x=v0; ov.y=v1; ov.z=v2; ov.w=v3;
          *(float4*)((float*)Out + oa) = ov;
        }
      }
    }
  }
}

// ---------------- logits ----------------
__global__ __launch_bounds__(256) void logits_kernel(const float* __restrict__ outC,
                                                     float* __restrict__ dst){
  const int b = blockIdx.x, seg = blockIdx.y;
  const int co = threadIdx.x;
  if (co >= 200) return;
  const float* base = outC + ((size_t)b*784 + seg*98)*200 + co;
  float s = 0.f;
  for (int p=0;p<98;++p) s += base[(size_t)p*200];
  atomicAdd(&dst[b*200+co], s*(1.f/784.f));
}

// ---------------- attention -> mask ----------------
__global__ __launch_bounds__(256) void atten_kernel(const float* __restrict__ outC,
                                                    const int* __restrict__ label,
                                                    float* __restrict__ mask){
  __shared__ float al[784];
  __shared__ float redn[256], redx[256];
  __shared__ unsigned char lab[200];
  const int b = blockIdx.x, tid = threadIdx.x;
  for (int i=tid;i<200;i+=256) lab[i] = label[b*200+i] > 0 ? 1 : 0;
  __syncthreads();
  for (int p=tid;p<784;p+=256){
    const float* row = outC + ((size_t)b*784+p)*200;
    float m = -__builtin_inff();
    for (int c=0;c<200;++c) if (lab[c]) m = fmaxf(m, row[c]);
    al[p] = fmaxf(m, 0.f);
  }
  __syncthreads();
  float mn = __builtin_inff(), mx = -__builtin_inff();
  for (int p=tid;p<784;p+=256){ float v=al[p]; mn=fminf(mn,v); mx=fmaxf(mx,v); }
  redn[tid]=mn; redx[tid]=mx; __syncthreads();
  for (int s2=128;s2>0;s2>>=1){
    if (tid<s2){ redn[tid]=fminf(redn[tid],redn[tid+s2]); redx[tid]=fmaxf(redx[tid],redx[tid+s2]); }
    __syncthreads();
  }
  mn = redn[0]; mx = redx[0];
  for (int p=tid;p<784;p+=256){
    float nrm = (al[p]-mn)/(mx-mn);
    mask[b*784+p] = (nrm >= 0.6f) ? 0.f : 1.f;
  }
}

// ---------------- erase ----------------
__global__ __launch_bounds__(256) void erase_kernel(const unsigned short* __restrict__ feats,
                                                    const float* __restrict__ mask,
                                                    unsigned short* __restrict__ dst){
  const int blk = blockIdx.x; const int b = blk/30, row = blk - b*30;
  const size_t base = ((size_t)b*960 + row*32)*512;
  for (int i=threadIdx.x; i<4096; i+=256){
    int col = i >> 7;
    float mv = 0.f;
    if (row>=1 && row<=28 && col>=1 && col<=28) mv = mask[b*784 + (row-1)*28 + (col-1)];
    uint2 v = make_uint2(0u,0u);
    if (mv > 0.5f) v = *(const uint2*)(feats + base + (size_t)i*4);
    *(uint2*)(dst + base + (size_t)i*4) = v;
  }
}

extern "C" void kernel_launch(void* const* d_in, const int* in_sizes, int n_in,
                              void* d_out, int out_size, void* d_ws, size_t ws_size,
                              hipStream_t stream){
  (void)in_sizes; (void)n_in; (void)out_size; (void)ws_size;
  const float* x   = (const float*)d_in[0];
  const int* label = (const int*)d_in[1];
  const float* w1a = (const float*)d_in[2];  const float* b1a = (const float*)d_in[3];
  const float* w2a = (const float*)d_in[4];  const float* b2a = (const float*)d_in[5];
  const float* w3a = (const float*)d_in[6];  const float* b3a = (const float*)d_in[7];
  const float* w1b = (const float*)d_in[8];  const float* b1b = (const float*)d_in[9];
  const float* w2b = (const float*)d_in[10]; const float* b2b = (const float*)d_in[11];
  const float* w3b = (const float*)d_in[12]; const float* b3b = (const float*)d_in[13];

  char* ws = (char*)d_ws;
  unsigned short* WtS = (unsigned short*)(ws);                 // [9][1024][512]  bf16 (+4KB guard)
  unsigned short* WtL = (unsigned short*)(ws + 9441280);       // [9][1024][1024] bf16 (+4KB guard)
  unsigned short* W3p = (unsigned short*)(ws + 28319744);      // [256][1024]     bf16 (+4KB guard)
  unsigned short* F   = (unsigned short*)(ws + 28848128);      // feats [32][960][512] (+4KB guard)
  unsigned short* G1  = (unsigned short*)(ws + 60309504);      // [32][960][1024] (+4KB guard)
  unsigned short* G2  = (unsigned short*)(ws + 123228160);     // [32][960][1024] (+4KB guard)
  float* outC  = (float*)(ws + 186146816);                     // [32][784][200] f32
  float* maskB = (float*)(ws + 206217216);                     // [32][784] f32
  float* logA = (float*)d_out;
  float* logB = logA + 6400;

  hipMemsetAsync(G1, 0, 62914560, stream);
  hipMemsetAsync(G2, 0, 62914560, stream);
  hipMemsetAsync(d_out, 0, 51200, stream);

  pool_kernel<<<1024,256,0,stream>>>(x, F);

  // ---- path A ----
  prep3x3<512><<<1024,256,0,stream>>>(w1a, WtS);
  conv3x3_v13<512><<<896,256,0,stream>>>(F, WtS, b1a, G1);
  prep3x3<1024><<<1024,256,0,stream>>>(w2a, WtL);
  conv3x3_v13<1024><<<896,256,0,stream>>>(G1, WtL, b2a, G2);
  prep1x1<<<256,256,0,stream>>>(w3a, W3p);
  conv_mfma<1024,false,false><<<dim3(2,128),512,0,stream>>>(G2, W3p, b3a, 200, outC);
  logits_kernel<<<dim3(32,8),256,0,stream>>>(outC, logA);
  atten_kernel<<<32,256,0,stream>>>(outC, label, maskB);
  erase_kernel<<<960,256,0,stream>>>(F, maskB, G1);

  // ---- path B ----
  prep3x3<512><<<1024,256,0,stream>>>(w1b, WtS);
  conv3x3_v13<512><<<896,256,0,stream>>>(G1, WtS, b1b, G2);
  prep3x3<1024><<<1024,256,0,stream>>>(w2b, WtL);
  conv3x3_v13<1024><<<896,256,0,stream>>>(G2, WtL, b2b, G1);
  prep1x1<<<256,256,0,stream>>>(w3b, W3p);
  conv_mfma<1024,false,false><<<dim3(2,128),512,0,stream>>>(G1, W3p, b3b, 200, outC);
  logits_kernel<<<dim3(32,8),256,0,stream>>>(outC, logB);
}

// Round 15
// 1434.480 us; speedup vs baseline: 1.1727x; 1.0662x over previous
//
#include <hip/hip_runtime.h>
#include <hip/hip_bf16.h>

typedef unsigned long long ull;
typedef __attribute__((ext_vector_type(8))) short short8;
typedef __attribute__((ext_vector_type(8))) __bf16 bf16x8;
typedef __attribute__((ext_vector_type(4))) float floatx4;

#define GLL16(gp, lp) __builtin_amdgcn_global_load_lds( \
  (__attribute__((address_space(1))) void*)(gp), \
  (__attribute__((address_space(3))) void*)(lp), 16, 0, 0)

#define WVM(N) asm volatile("s_waitcnt vmcnt(" #N ")" ::: "memory")

__device__ __forceinline__ floatx4 mfma16(short8 a, short8 b, floatx4 c){
  return __builtin_amdgcn_mfma_f32_16x16x32_bf16(
      __builtin_bit_cast(bf16x8, a), __builtin_bit_cast(bf16x8, b), c, 0, 0, 0);
}

// pack two f32 -> two bf16 (RNE) in one u32 (lo = a, hi = b)
__device__ __forceinline__ unsigned pkbf(float a, float b){
  unsigned ua = __float_as_uint(a), ub = __float_as_uint(b);
  ua += 0x7fffu + ((ua >> 16) & 1u);
  ub += 0x7fffu + ((ub >> 16) & 1u);
  return (ua >> 16) | (ub & 0xffff0000u);
}

// ---------------- avg-pool 3x3 -> channel-last padded bf16 ----------------
__global__ __launch_bounds__(256) void pool_kernel(const float* __restrict__ x,
                                                   unsigned short* __restrict__ out){
  __shared__ float xs[16*784];
  const int tid = threadIdx.x;
  const int b = blockIdx.x >> 5, cg = blockIdx.x & 31;
  const float* src = x + ((size_t)b*512 + cg*16)*784;
  for (int i=tid;i<16*784;i+=256) xs[i]=src[i];
  __syncthreads();
  unsigned* dst = (unsigned*)out + ((size_t)b*960)*256 + cg*8;
  for (int o=tid;o<30*32*8;o+=256){
    int cip = o & 7, pos = o >> 3;
    int row = pos >> 5, col = pos & 31;
    float s0=0.f, s1=0.f;
    if (row>=1 && row<=28 && col>=1 && col<=28){
      int h=row-1, w=col-1;
      const float* p0 = &xs[(cip*2)*784];
      const float* p1 = p0 + 784;
      #pragma unroll
      for (int dh=-1;dh<=1;++dh){ int hh=h+dh; if ((unsigned)hh<28u){
        #pragma unroll
        for (int dw=-1;dw<=1;++dw){ int ww=w+dw; if((unsigned)ww<28u){
          s0 += p0[hh*28+ww]; s1 += p1[hh*28+ww]; } } } }
      s0 /= 9.f; s1 /= 9.f;
    }
    dst[(size_t)pos*256 + cip] = pkbf(s0, s1);
  }
}

// ---------------- weight transform: OIHW f32 -> [tap][1024][CIN] bf16 ----------------
template<int CIN>
__global__ __launch_bounds__(256) void prep3x3(const float* __restrict__ w,
                                               unsigned short* __restrict__ Wt){
  __shared__ float wsm[CIN*9];
  const int co = blockIdx.x, tid = threadIdx.x;
  const float* src = w + (size_t)co*(CIN*9);
  for (int i=tid;i<CIN*9;i+=256) wsm[i]=src[i];
  __syncthreads();
  for (int o=tid;o<9*(CIN/2);o+=256){
    int t = o/(CIN/2), cp = o - t*(CIN/2);
    unsigned v = pkbf(wsm[(cp*2)*9+t], wsm[(cp*2+1)*9+t]);
    ((unsigned*)Wt)[(((size_t)t*1024+co)*CIN>>1) + cp] = v;
  }
}

// w3 [200][1024] f32 -> [256][1024] bf16, rows 200..255 zero
__global__ __launch_bounds__(256) void prep1x1(const float* __restrict__ w3,
                                               unsigned short* __restrict__ Wp){
  const int row = blockIdx.x, tid = threadIdx.x;
  unsigned* dst = (unsigned*)Wp + (size_t)row*512;
  if (row < 200){
    const float* src = w3 + (size_t)row*1024;
    for (int j=tid;j<512;j+=256) dst[j] = pkbf(src[2*j], src[2*j+1]);
  } else {
    for (int j=tid;j<512;j+=256) dst[j] = 0u;
  }
}

// ======== 3x3 conv v9 (round-9 exact geometry, setprio removed): 64ci phases, 2 blocks/CU ========
// Grid 1024 = 8 co-groups(128co, XCD-pinned) x 32 b x 4 row-tiles of 8 rows (r0 = rb*8).
// Block 256 thr = 4 waves (2 cog x 2 pg); wave tile 64co x 112px, acc[4][7] (AGPR).
// LDS 72KB: A 2 x 16KB dbuf [128co][64ci] staged 1 phase ahead; B single 40KB
// [10rows][32cols][64ci] staged at chunk boundary. Phase: stage A(t+1) -> reads (2 ksteps
// via ^64) + 56 MFMA -> WVM(0) (GLL ~2k cyc old) -> barrier. t==0,c>0: WVM(4)+barrier for B.
// Plateau note (r8-r13): LDS-read floor ~250us/CU and MFMA floor ~228us/CU alternate at
// 2 waves/SIMD (regfile cap: 112 acc AGPR + ~115 VGPR) -> ~48% MfmaUtil, ~430us/dispatch.
template<int CIN>
__global__ __launch_bounds__(256, 2) void conv3x3_v9(
    const unsigned short* __restrict__ X,
    const unsigned short* __restrict__ Wt,
    const float* __restrict__ bias,
    unsigned short* __restrict__ Out)
{
  constexpr int NCH = CIN/64;
  constexpr size_t CB = (size_t)CIN*2;
  constexpr size_t TAPSTR = (size_t)1024*CB;
  __shared__ char Als[32768];   // 2 x 16384: [128co][128B=64ci]
  __shared__ char Bls[40960];   // [10rows][32cols][128B=64ci]

  const int tid = threadIdx.x;
  const int l = tid & 63, wv = tid >> 6;        // 4 waves
  const int cog = wv & 1, pg = wv >> 1;
  const int bid = blockIdx.x;
  const int co0 = (bid & 7) << 7;               // 128-co panel per XCD
  const int y = bid >> 3;                       // 0..127
  const int b = y >> 2, rb = y & 3;
  const int r0 = rb << 3;                       // first output row: 0,8,16,24
  const bool active = (pg == 0) || (rb < 3);

  // staging lane pre-swizzle for 128B-row units (linear LDS dest + inv-swizzled source)
  const int sb = (l*16) ^ (((l>>3)&7)<<4);
  const int sr = sb >> 7;                       // row 0..7 within 1KB unit
  const int sw = sb & 127;

  // A: 16 units of 8 co-rows x 128B; wave stages units wv*4..wv*4+3
  ull aS[4];
  #pragma unroll
  for (int k=0;k<4;++k)
    aS[k] = (ull)Wt + (size_t)(co0 + (wv*4+k)*8 + sr)*CB + sw;
  // B: 40 units of 8 px x 128B (10 padded rows r0..r0+9 x 32 cols); wave stages wv+4k
  ull bS[10];
  #pragma unroll
  for (int k=0;k<10;++k){
    int q = (wv + 4*k)*8 + sr;                  // px 0..319
    int trow = q >> 5, tcol = q & 31;
    int ir = r0 + trow; if (ir > 29) ir = 29;
    bS[k] = (ull)X + ((size_t)b*960 + ir*32 + tcol)*CB + sw;
  }

  const int jl = l & 15, g = l >> 4;
  int paE[4];
  #pragma unroll
  for (int m=0;m<4;++m){
    int xo = (cog*64 + m*16 + jl)*128 + g*16;
    paE[m] = xo ^ (((xo>>7)&7)<<4);             // kstep via ^64 (bit6 below XOR src, no carry)
  }
  int pbS[3][7];
  #pragma unroll
  for (int f=0;f<7;++f){
    int p = pg*112 + f*16 + jl;
    int hl = p/28, cl = p - hl*28;
    #pragma unroll
    for (int ss=0;ss<3;++ss){
      int xo = (hl*32 + cl + ss)*128 + g*16;
      pbS[ss][f] = xo ^ (((xo>>7)&7)<<4);       // + rr*4096 post-swz (bits>=12); ^64 for ks1
    }
  }

  floatx4 acc[4][7];
  #pragma unroll
  for (int m=0;m<4;++m)
    #pragma unroll
    for (int f=0;f<7;++f) acc[m][f] = (floatx4){0.f,0.f,0.f,0.f};

  // ---- prologue: B(c0) 10 GLL/wave; A(c0,tap0) 4 GLL/wave -> slot 0 ----
  #pragma unroll
  for (int k=0;k<10;++k) GLL16((const void*)bS[k], Bls + (wv + 4*k)*1024);
  #pragma unroll
  for (int k=0;k<4;++k)  GLL16((const void*)aS[k], Als + (wv*4+k)*1024);
  WVM(0);
  __builtin_amdgcn_s_barrier();

  #pragma unroll 1
  for (int c=0;c<NCH;++c){
    #pragma unroll
    for (int t=0;t<9;++t){
      const int rr = t/3, ss = t - rr*3;
      const int cur = ((c + t) & 1)*16384;
      const int nxt = cur ^ 16384;
      // --- stage A for next phase (tap t+1, or tap0 of chunk c+1) ---
      const int ntap = (t<8) ? t+1 : 0;
      const size_t aoff = (size_t)ntap*TAPSTR + (size_t)(t<8 ? c : c+1)*128;
      #pragma unroll
      for (int k=0;k<4;++k)
        GLL16((const void*)(aS[k] + aoff), Als + nxt + (wv*4+k)*1024);
      // --- B-landing sync at chunk start (B staged at previous chunk boundary) ---
      if (t == 0 && c > 0){
        WVM(4);                                 // 10 B drained; my 4 A float
        __builtin_amdgcn_s_barrier();
      }
      // --- fragment reads + MFMA, 2 ksteps of 32ci ---
      if (active){
        #pragma unroll
        for (int ks=0;ks<2;++ks){
          const int kx = ks*64;
          const char* ap = Als + cur;
          short8 a0 = *(const short8*)(ap + (paE[0]^kx));
          short8 a1 = *(const short8*)(ap + (paE[1]^kx));
          short8 a2 = *(const short8*)(ap + (paE[2]^kx));
          short8 a3 = *(const short8*)(ap + (paE[3]^kx));
          short8 bv[7];
          #pragma unroll
          for (int f=0;f<7;++f)
            bv[f] = *(const short8*)(Bls + ((pbS[ss][f]^kx) + rr*4096));
          #pragma unroll
          for (int f=0;f<7;++f){
            acc[0][f] = mfma16(a0, bv[f], acc[0][f]);
            acc[1][f] = mfma16(a1, bv[f], acc[1][f]);
            acc[2][f] = mfma16(a2, bv[f], acc[2][f]);
            acc[3][f] = mfma16(a3, bv[f], acc[3][f]);
          }
        }
      }
      WVM(0);                                   // A(t+1) landed (issued ~2k cyc ago)
      __builtin_amdgcn_s_barrier();
    }
    // --- chunk boundary: stage B(c+1) into the single buffer (reads drained) ---
    if (c + 1 < NCH){
      #pragma unroll
      for (int k=0;k<10;++k)
        GLL16((const void*)(bS[k] + (size_t)(c+1)*128), Bls + (wv + 4*k)*1024);
    }
  }

  if (!active) return;

  // ---- epilogue: bias + ReLU + bf16 pack ----
  #pragma unroll
  for (int m=0;m<4;++m){
    const int coL = cog*64 + m*16 + g*4;
    const float4 bv4 = *(const float4*)&bias[co0 + coL];
    #pragma unroll
    for (int f=0;f<7;++f){
      int pp = pg*112 + f*16 + jl;
      int hl = pp/28, cl = pp - hl*28;
      float v0 = fmaxf(acc[m][f][0] + bv4.x, 0.f);
      float v1 = fmaxf(acc[m][f][1] + bv4.y, 0.f);
      float v2 = fmaxf(acc[m][f][2] + bv4.z, 0.f);
      float v3 = fmaxf(acc[m][f][3] + bv4.w, 0.f);
      uint2 pk; pk.x = pkbf(v0,v1); pk.y = pkbf(v2,v3);
      size_t oa = ((size_t)b*960 + (size_t)(r0 + hl + 1)*32 + (cl + 1))*1024 + (co0 + coL);
      *(uint2*)(Out + oa) = pk;
    }
  }
}

// ---------------- 1x1 conv via MFMA ----------------
template<int CIN, bool K3, bool BF16OUT>
__global__ __launch_bounds__(512, 2) void conv_mfma(
    const unsigned short* __restrict__ X,
    const unsigned short* __restrict__ Wt,
    const float* __restrict__ bias, int biasN,
    void* __restrict__ Out)
{
  constexpr int T9 = K3 ? 9 : 1;
  constexpr int NA = K3 ? 9 : 1;
  __shared__ short Als[T9*4096];
  __shared__ short Bls[10240];
  __shared__ float biasLs[128];

  const int tid = threadIdx.x;
  const int l = tid & 63, wv = tid >> 6;
  const int wc = wv & 3, wp = wv >> 2;
  const int co0 = blockIdx.x << 7;
  const int by = blockIdx.y;
  const int b = by >> 2, rb = by & 3;
  const int r0 = rb << 3;
  const int nrh = (rb < 3) ? 10 : 6;
  const int NB = 2*nrh;
  const bool active = (wp == 0) || (rb < 3);

  if (tid < 128) biasLs[tid] = (co0 + tid < biasN) ? bias[co0 + tid] : 0.f;

  const size_t laneOff = (size_t)(l >> 2)*(CIN*2) + (size_t)(l & 3)*16;

  ull aB[NA];
  #pragma unroll
  for (int j=0;j<NA;++j){
    int k = wv*NA + j;
    int t = K3 ? (k >> 3) : 0;
    int cog2 = K3 ? (k & 7) : k;
    aB[j] = (ull)Wt + ((size_t)(t*1024 + co0 + cog2*16)*(CIN*2)) + laneOff;
  }
  const ull xBase = (ull)X + ((size_t)b*960)*(CIN*2) + (size_t)(r0*32)*(CIN*2) + laneOff;
  ull bB0=0, bB1=0, bB2=0; int nb=0;
  if (wv < NB)      { bB0 = xBase + (size_t)(wv*16)*(CIN*2);      nb = 1; }
  if (wv + 8 < NB)  { bB1 = xBase + (size_t)((wv+8)*16)*(CIN*2);  nb = 2; }
  if (wv + 16 < NB) { bB2 = xBase + (size_t)((wv+16)*16)*(CIN*2); nb = 3; }

  const int jl = l & 15, g = l >> 4;
  int paE[2];
  #pragma unroll
  for (int m=0;m<2;++m) paE[m] = (wc*32 + m*16 + jl)*32 + g*8;
  int pbE[7], ph[7], pc[7];
  #pragma unroll
  for (int f=0;f<7;++f){
    int p = wp*112 + f*16 + jl;
    int hl = p / 28, cl = p - hl*28;
    ph[f]=hl; pc[f]=cl;
    pbE[f] = (hl*32 + cl)*32 + g*8;
  }

  floatx4 acc[2][7];
  #pragma unroll
  for (int m=0;m<2;++m)
    #pragma unroll
    for (int f=0;f<7;++f) acc[m][f] = (floatx4){0.f,0.f,0.f,0.f};

  const int NCH = CIN/32;
  for (int c=0;c<NCH;++c){
    if (c) __syncthreads();
    const size_t cOff = (size_t)c*64;
    #pragma unroll
    for (int j=0;j<NA;++j)
      GLL16((const void*)(aB[j] + cOff), (char*)Als + (wv*NA + j)*1024);
    GLL16((const void*)(bB0 + cOff), (char*)Bls + wv*1024);
    if (nb > 1) GLL16((const void*)(bB1 + cOff), (char*)Bls + (wv+8)*1024);
    if (nb > 2) GLL16((const void*)(bB2 + cOff), (char*)Bls + (wv+16)*1024);
    __syncthreads();
    if (active){
      #pragma unroll
      for (int t=0;t<T9;++t){
        const int tA = t*4096;
        const int tB = K3 ? (((t/3)*32 + (t - (t/3)*3))*32) : ((1*32+1)*32);
        short8 a0 = *(const short8*)&Als[tA + paE[0]];
        short8 a1 = *(const short8*)&Als[tA + paE[1]];
        #pragma unroll
        for (int f=0;f<7;++f){
          short8 bvv = *(const short8*)&Bls[tB + pbE[f]];
          acc[0][f] = mfma16(a0, bvv, acc[0][f]);
          acc[1][f] = mfma16(a1, bvv, acc[1][f]);
        }
      }
    }
  }

  if (!active) return;

  #pragma unroll
  for (int m=0;m<2;++m){
    const int coL = wc*32 + m*16 + g*4;
    const float4 bv4 = *(const float4*)&biasLs[coL];
    #pragma unroll
    for (int f=0;f<7;++f){
      float v0 = acc[m][f][0] + bv4.x;
      float v1 = acc[m][f][1] + bv4.y;
      float v2 = acc[m][f][2] + bv4.z;
      float v3 = acc[m][f][3] + bv4.w;
      if constexpr (BF16OUT){
        v0=fmaxf(v0,0.f); v1=fmaxf(v1,0.f); v2=fmaxf(v2,0.f); v3=fmaxf(v3,0.f);
        uint2 pk; pk.x = pkbf(v0,v1); pk.y = pkbf(v2,v3);
        size_t oa = ((size_t)b*960 + (size_t)(r0 + ph[f] + 1)*32 + (pc[f]+1))*1024 + (co0 + coL);
        *(uint2*)((unsigned short*)Out + oa) = pk;
      } else {
        int co = co0 + coL;
        if (co < 200){
          int p = wp*112 + f*16 + jl;
          size_t oa = ((size_t)b*784 + (size_t)(r0*28) + p)*200 + co;
          float4 ov; ov.x=v0; ov.y=v1; ov.z=v2; ov.w=v3;
          *(float4*)((float*)Out + oa) = ov;
        }
      }
    }
  }
}

// ---------------- logits ----------------
__global__ __launch_bounds__(256) void logits_kernel(const float* __restrict__ outC,
                                                     float* __restrict__ dst){
  const int b = blockIdx.x, seg = blockIdx.y;
  const int co = threadIdx.x;
  if (co >= 200) return;
  const float* base = outC + ((size_t)b*784 + seg*98)*200 + co;
  float s = 0.f;
  for (int p=0;p<98;++p) s += base[(size_t)p*200];
  atomicAdd(&dst[b*200+co], s*(1.f/784.f));
}

// ---------------- attention -> mask ----------------
__global__ __launch_bounds__(256) void atten_kernel(const float* __restrict__ outC,
                                                    const int* __restrict__ label,
                                                    float* __restrict__ mask){
  __shared__ float al[784];
  __shared__ float redn[256], redx[256];
  __shared__ unsigned char lab[200];
  const int b = blockIdx.x, tid = threadIdx.x;
  for (int i=tid;i<200;i+=256) lab[i] = label[b*200+i] > 0 ? 1 : 0;
  __syncthreads();
  for (int p=tid;p<784;p+=256){
    const float* row = outC + ((size_t)b*784+p)*200;
    float m = -__builtin_inff();
    for (int c=0;c<200;++c) if (lab[c]) m = fmaxf(m, row[c]);
    al[p] = fmaxf(m, 0.f);
  }
  __syncthreads();
  float mn = __builtin_inff(), mx = -__builtin_inff();
  for (int p=tid;p<784;p+=256){ float v=al[p]; mn=fminf(mn,v); mx=fmaxf(mx,v); }
  redn[tid]=mn; redx[tid]=mx; __syncthreads();
  for (int s2=128;s2>0;s2>>=1){
    if (tid<s2){ redn[tid]=fminf(redn[tid],redn[tid+s2]); redx[tid]=fmaxf(redx[tid],redx[tid+s2]); }
    __syncthreads();
  }
  mn = redn[0]; mx = redx[0];
  for (int p=tid;p<784;p+=256){
    float nrm = (al[p]-mn)/(mx-mn);
    mask[b*784+p] = (nrm >= 0.6f) ? 0.f : 1.f;
  }
}

// ---------------- erase ----------------
__global__ __launch_bounds__(256) void erase_kernel(const unsigned short* __restrict__ feats,
                                                    const float* __restrict__ mask,
                                                    unsigned short* __restrict__ dst){
  const int blk = blockIdx.x; const int b = blk/30, row = blk - b*30;
  const size_t base = ((size_t)b*960 + row*32)*512;
  for (int i=threadIdx.x; i<4096; i+=256){
    int col = i >> 7;
    float mv = 0.f;
    if (row>=1 && row<=28 && col>=1 && col<=28) mv = mask[b*784 + (row-1)*28 + (col-1)];
    uint2 v = make_uint2(0u,0u);
    if (mv > 0.5f) v = *(const uint2*)(feats + base + (size_t)i*4);
    *(uint2*)(dst + base + (size_t)i*4) = v;
  }
}

extern "C" void kernel_launch(void* const* d_in, const int* in_sizes, int n_in,
                              void* d_out, int out_size, void* d_ws, size_t ws_size,
                              hipStream_t stream){
  (void)in_sizes; (void)n_in; (void)out_size; (void)ws_size;
  const float* x   = (const float*)d_in[0];
  const int* label = (const int*)d_in[1];
  const float* w1a = (const float*)d_in[2];  const float* b1a = (const float*)d_in[3];
  const float* w2a = (const float*)d_in[4];  const float* b2a = (const float*)d_in[5];
  const float* w3a = (const float*)d_in[6];  const float* b3a = (const float*)d_in[7];
  const float* w1b = (const float*)d_in[8];  const float* b1b = (const float*)d_in[9];
  const float* w2b = (const float*)d_in[10]; const float* b2b = (const float*)d_in[11];
  const float* w3b = (const float*)d_in[12]; const float* b3b = (const float*)d_in[13];

  char* ws = (char*)d_ws;
  unsigned short* WtS = (unsigned short*)(ws);                 // [9][1024][512]  bf16 (+4KB guard)
  unsigned short* WtL = (unsigned short*)(ws + 9441280);       // [9][1024][1024] bf16 (+4KB guard)
  unsigned short* W3p = (unsigned short*)(ws + 28319744);      // [256][1024]     bf16 (+4KB guard)
  unsigned short* F   = (unsigned short*)(ws + 28848128);      // feats [32][960][512] (+4KB guard)
  unsigned short* G1  = (unsigned short*)(ws + 60309504);      // [32][960][1024] (+4KB guard)
  unsigned short* G2  = (unsigned short*)(ws + 123228160);     // [32][960][1024] (+4KB guard)
  float* outC  = (float*)(ws + 186146816);                     // [32][784][200] f32
  float* maskB = (float*)(ws + 206217216);                     // [32][784] f32
  float* logA = (float*)d_out;
  float* logB = logA + 6400;

  hipMemsetAsync(G1, 0, 62914560, stream);
  hipMemsetAsync(G2, 0, 62914560, stream);
  hipMemsetAsync(d_out, 0, 51200, stream);

  pool_kernel<<<1024,256,0,stream>>>(x, F);

  // ---- path A ----
  prep3x3<512><<<1024,256,0,stream>>>(w1a, WtS);
  conv3x3_v9<512><<<1024,256,0,stream>>>(F, WtS, b1a, G1);
  prep3x3<1024><<<1024,256,0,stream>>>(w2a, WtL);
  conv3x3_v9<1024><<<1024,256,0,stream>>>(G1, WtL, b2a, G2);
  prep1x1<<<256,256,0,stream>>>(w3a, W3p);
  conv_mfma<1024,false,false><<<dim3(2,128),512,0,stream>>>(G2, W3p, b3a, 200, outC);
  logits_kernel<<<dim3(32,8),256,0,stream>>>(outC, logA);
  atten_kernel<<<32,256,0,stream>>>(outC, label, maskB);
  erase_kernel<<<960,256,0,stream>>>(F, maskB, G1);

  // ---- path B ----
  prep3x3<512><<<1024,256,0,stream>>>(w1b, WtS);
  conv3x3_v9<512><<<1024,256,0,stream>>>(G1, WtS, b1b, G2);
  prep3x3<1024><<<1024,256,0,stream>>>(w2b, WtL);
  conv3x3_v9<1024><<<1024,256,0,stream>>>(G2, WtL, b2b, G1);
  prep1x1<<<256,256,0,stream>>>(w3b, W3p);
  conv_mfma<1024,false,false><<<dim3(2,128),512,0,stream>>>(G1, W3p, b3b, 200, outC);
  logits_kernel<<<dim3(32,8),256,0,stream>>>(outC, logB);
}